// Round 4
// baseline (269.313 us; speedup 1.0000x reference)
//
#include <hip/hip_runtime.h>
#include <hip/hip_bf16.h>
#include <math.h>

typedef __attribute__((ext_vector_type(8))) short short8;
typedef __attribute__((ext_vector_type(4))) float f32x4;

#define PSTRIDE 4160   // partials row stride in floats (4096 + 64 pad, non-pow2)

// round-to-nearest-even fp32 -> bf16 bits
__device__ __forceinline__ unsigned int bf16_rn(float x) {
    unsigned int u = __float_as_uint(x);
    return (u + 0x7FFFu + ((u >> 16) & 1u)) >> 16;
}

// ---------------------------------------------------------------------------
// Kernel 1: per-row cross-entropy + logits pass-through copy.
// ---------------------------------------------------------------------------
__global__ __launch_bounds__(256) void ce_kernel(
    const float* __restrict__ logits, const int* __restrict__ target,
    float* __restrict__ out_copy, float* __restrict__ ce_rows)
{
    const int row = blockIdx.x;
    const float* x = logits + row * 1000;
    const int t = threadIdx.x;
    __shared__ float red[256];

    float m = -INFINITY;
    for (int i = t; i < 1000; i += 256) {
        float v = x[i];
        out_copy[row * 1000 + i] = v;
        m = fmaxf(m, v);
    }
    red[t] = m; __syncthreads();
    for (int s = 128; s > 0; s >>= 1) {
        if (t < s) red[t] = fmaxf(red[t], red[t + s]);
        __syncthreads();
    }
    m = red[0];
    __syncthreads();

    float ssum = 0.f;
    for (int i = t; i < 1000; i += 256) ssum += expf(x[i] - m);
    red[t] = ssum; __syncthreads();
    for (int s = 128; s > 0; s >>= 1) {
        if (t < s) red[t] += red[t + s];
        __syncthreads();
    }
    if (t == 0) {
        double lse = (double)m + log((double)red[0]);
        int tg = target[row];
        ce_rows[row] = (float)(-((double)x[tg] - lse));
    }
}

// ---------------------------------------------------------------------------
// Kernel 2: repack fp32 rows -> fragment-ordered hi/lo bf16 slab.
// Slab layout per 128-k chunk (32768 B):
//   offset = w*8192 + tm*2048 + h*1024 + quad*256 + m*16, h in {hi=0, lo=1},
// holding X[row=tm*16+m][k=c*128+w*32+quad*8 .. +7] as 8 bf16 (16 B).
// Block = (f, r8, kq): 8 rows (m covers 8 consecutive -> 128 B-contiguous
// write granules, all from this block), contiguous k-span reads per wave.
// ---------------------------------------------------------------------------
__global__ __launch_bounds__(256) void repack_kernel(
    const float* __restrict__ X, char* __restrict__ slab, int D, int Q)
{
    const int blk = blockIdx.x;
    const int f = blk / (8 * Q);
    const int rem = blk % (8 * Q);
    const int r8 = rem / Q;
    int kq = rem % Q;
    kq = (kq * 5) % Q;                       // decorrelate concurrent k-spans
    const int kspan = D / Q;                 // multiple of 512
    const int kIters = kspan >> 9;           // 512 floats per wave-iteration
    const int k0 = kq * kspan;

    const int wave = threadIdx.x >> 6, lane = threadIdx.x & 63;
    const int chunksPerFeature = D >> 7;
    char* slabF = slab + (size_t)f * chunksPerFeature * 32768;
    const float* xf = X + (size_t)f * 64 * D;

    const int it0 = (blk * 7) & (kIters - 1);
#pragma unroll
    for (int sub = 0; sub < 2; ++sub) {
        const int row = r8 * 8 + sub * 4 + wave;
        const int tm = row >> 4, m = row & 15;
        const float* xr = xf + (size_t)row * D;
        for (int i = 0; i < kIters; ++i) {
            int it = (it0 + i) & (kIters - 1);
            int k = k0 + it * 512 + lane * 8;
            float4 a = *(const float4*)(xr + k);
            float4 b = *(const float4*)(xr + k + 4);
            float vv[8] = {a.x, a.y, a.z, a.w, b.x, b.y, b.z, b.w};
            short8 hv, lv;
#pragma unroll
            for (int j = 0; j < 8; ++j) {
                unsigned int hb = bf16_rn(vv[j]);
                hv[j] = (short)hb;
                lv[j] = (short)bf16_rn(vv[j] - __uint_as_float(hb << 16));
            }
            int gc = k >> 7, r = k & 127, w = r >> 5, quad = (r >> 3) & 3;
            char* base = slabF + (size_t)gc * 32768 + w * 8192 + tm * 2048
                         + quad * 256 + m * 16;
            *(short8*)base = hv;
            *(short8*)(base + 1024) = lv;
        }
    }
}

// ---------------------------------------------------------------------------
// Kernel 3: Gram from the slab. Block = (f, 4-chunk range), reads are pure
// sequential 1 KB-per-instruction dwordx4; 48 MFMAs per chunk per wave;
// no barriers in the loop; LDS cross-wave reduce (layout validated R2/R3).
// ---------------------------------------------------------------------------
__global__ __launch_bounds__(256) void gram_kernel(
    const char* __restrict__ slab, float* __restrict__ partials,
    int rangesPerFeature, int chunksPerFeature)
{
    __shared__ float kbuf[4096];
    const int blk = blockIdx.x;
    const int f = blk / rangesPerFeature;
    int local = blk % rangesPerFeature;
    local = (local * 13) % rangesPerFeature;     // spread concurrent ranges
    const char* slabR = slab + ((size_t)f * chunksPerFeature + local * 4) * 32768;

    const int t = threadIdx.x;
    const int wave = t >> 6, lane = t & 63;
    const int m = lane & 15, quad = lane >> 4;
    const int foff = wave * 8192 + quad * 256 + m * 16;

    f32x4 acc[4][4];
#pragma unroll
    for (int i = 0; i < 4; ++i)
#pragma unroll
        for (int j = 0; j < 4; ++j) acc[i][j] = (f32x4)0.f;

    const int rot = blk & 3;
    for (int ci = 0; ci < 4; ++ci) {
        const int c = (ci + rot) & 3;
        const char* cb = slabR + (size_t)c * 32768 + foff;
        short8 hf[4], lf[4];
#pragma unroll
        for (int tm = 0; tm < 4; ++tm) {
            hf[tm] = *(const short8*)(cb + tm * 2048);
            lf[tm] = *(const short8*)(cb + tm * 2048 + 1024);
        }
#pragma unroll
        for (int tm = 0; tm < 4; ++tm)
#pragma unroll
            for (int tn = 0; tn < 4; ++tn) {
                acc[tm][tn] = __builtin_amdgcn_mfma_f32_16x16x32_bf16(
                    hf[tm], hf[tn], acc[tm][tn], 0, 0, 0);
                acc[tm][tn] = __builtin_amdgcn_mfma_f32_16x16x32_bf16(
                    hf[tm], lf[tn], acc[tm][tn], 0, 0, 0);
                acc[tm][tn] = __builtin_amdgcn_mfma_f32_16x16x32_bf16(
                    lf[tm], hf[tn], acc[tm][tn], 0, 0, 0);
            }
    }

    __syncthreads();
    if (wave == 0) {
#pragma unroll
        for (int tm = 0; tm < 4; ++tm)
#pragma unroll
            for (int tn = 0; tn < 4; ++tn)
#pragma unroll
                for (int r = 0; r < 4; ++r)
                    kbuf[(tm * 16 + quad * 4 + r) * 64 + tn * 16 + m] = acc[tm][tn][r];
    }
    __syncthreads();
    if (wave != 0) {
#pragma unroll
        for (int tm = 0; tm < 4; ++tm)
#pragma unroll
            for (int tn = 0; tn < 4; ++tn)
#pragma unroll
                for (int r = 0; r < 4; ++r)
                    atomicAdd(&kbuf[(tm * 16 + quad * 4 + r) * 64 + tn * 16 + m],
                              acc[tm][tn][r]);
    }
    __syncthreads();

    float4* outp = (float4*)(partials + (size_t)blk * PSTRIDE);
    const float4* kb4 = (const float4*)kbuf;
    for (int e = t; e < 1024; e += 256) outp[e] = kb4[e];
}

// ---------------------------------------------------------------------------
// Kernel 4: sum partials -> K[f], zero diagonal. singleF<0: grid 448,
// f=blk>>6, bases from cntA/cntB. singleF>=0: grid 64, base 0.
// ---------------------------------------------------------------------------
__global__ __launch_bounds__(256) void reduce_kernel(
    const float* __restrict__ partials, float* __restrict__ K,
    int cntA, int cntB, int singleF)
{
    __shared__ double red[256];
    int f, eblk, base, cnt;
    if (singleF < 0) {
        f = blockIdx.x >> 6; eblk = blockIdx.x & 63;
        base = (f < 3) ? f * cntA : 3 * cntA + (f - 3) * cntB;
        cnt = (f < 3) ? cntA : cntB;
    } else {
        f = singleF; eblk = blockIdx.x; base = 0;
        cnt = (f < 3) ? cntA : cntB;
    }
    const int e = (eblk << 6) + (threadIdx.x & 63);
    const int jg = threadIdx.x >> 6;

    double s0 = 0.0, s1 = 0.0;
    int j = jg;
    for (; j + 4 < cnt; j += 8) {
        s0 += (double)partials[(size_t)(base + j) * PSTRIDE + e];
        s1 += (double)partials[(size_t)(base + j + 4) * PSTRIDE + e];
    }
    for (; j < cnt; j += 4)
        s0 += (double)partials[(size_t)(base + j) * PSTRIDE + e];
    red[threadIdx.x] = s0 + s1;
    __syncthreads();
    if (jg == 0) {
        double tot = red[threadIdx.x] + red[threadIdx.x + 64]
                   + red[threadIdx.x + 128] + red[threadIdx.x + 192];
        int rr = e >> 6, cc = e & 63;
        K[f * 4096 + e] = (rr == cc) ? 0.f : (float)tot;
    }
}

// ---------------------------------------------------------------------------
// Kernel 5: one block per (i,j) pair -> unbiased HSIC in fp64.
// ---------------------------------------------------------------------------
__global__ __launch_bounds__(256) void hsic_kernel(
    const float* __restrict__ K, double* __restrict__ hsic_out)
{
    const int p = blockIdx.x;
    int i, j;
    if (p < 9) { i = p / 3; j = p % 3; }
    else       { int q = p - 9; i = 3 + q / 4; j = 3 + q % 4; }
    const float* Ki = K + i * 4096;
    const float* Kj = K + j * 4096;
    const int t = threadIdx.x;

    __shared__ double red[256];
    __shared__ double ri[64], rj[64];

    double local = 0.0;
    for (int e = t; e < 4096; e += 256)
        local += (double)Ki[e] * (double)Kj[e];
    red[t] = local; __syncthreads();
    for (int s = 128; s > 0; s >>= 1) {
        if (t < s) red[t] += red[t + s];
        __syncthreads();
    }

    if (t < 64) {
        double s = 0.0;
        for (int mc = 0; mc < 64; ++mc) s += (double)Ki[t * 64 + mc];
        ri[t] = s;
    } else if (t < 128) {
        int n = t - 64;
        double s = 0.0;
        for (int mc = 0; mc < 64; ++mc) s += (double)Kj[n * 64 + mc];
        rj[n] = s;
    }
    __syncthreads();

    if (t == 0) {
        double tr = red[0];
        double rr = 0.0, si = 0.0, sj = 0.0;
        for (int n = 0; n < 64; ++n) {
            rr += ri[n] * rj[n];
            si += ri[n];
            sj += rj[n];
        }
        const double N = 64.0;
        const double c1 = (N - 1.0) * (N - 2.0);
        const double c2 = N - 2.0;
        const double c3 = N * (N - 3.0);
        hsic_out[p] = (tr + si * sj / c1 - 2.0 * rr / c2) / c3;
    }
}

// ---------------------------------------------------------------------------
// Kernel 6: combine -> loss.
// ---------------------------------------------------------------------------
__global__ __launch_bounds__(64) void final_kernel(
    const double* __restrict__ hsic, const float* __restrict__ ce_rows,
    float* __restrict__ out_loss)
{
    if (threadIdx.x != 0) return;
    double ce = 0.0;
    for (int n = 0; n < 64; ++n) ce += (double)ce_rows[n];
    ce /= 64.0;

    double cka_total = 0.0;
    for (int i = 0; i < 3; ++i)
        for (int j = 0; j < 3; ++j)
            cka_total += hsic[i * 3 + j] / sqrt(hsic[i * 3 + i] * hsic[j * 3 + j]);
    for (int i = 0; i < 4; ++i)
        for (int j = 0; j < 4; ++j)
            cka_total += hsic[9 + i * 4 + j] / sqrt(hsic[9 + i * 4 + i] * hsic[9 + j * 4 + j]);

    out_loss[0] = (float)(ce + 0.1 * cka_total);
}

// ---------------------------------------------------------------------------
extern "C" void kernel_launch(void* const* d_in, const int* in_sizes, int n_in,
                              void* d_out, int out_size, void* d_ws, size_t ws_size,
                              hipStream_t stream)
{
    const float* output  = (const float*)d_in[0];
    const int*   target  = (const int*)d_in[1];
    const float* feats_a = (const float*)d_in[2];
    const float* feats_b = (const float*)d_in[3];
    float* out = (float*)d_out;

    char* ws = (char*)d_ws;
    float*  K       = (float*)ws;                 // 114688 B
    float*  ce_rows = (float*)(ws + 114688);      // 256 B
    double* hsic    = (double*)(ws + 114944);     // 200 B
    char*   slab    = ws + 131072;

    const size_t slabAll = (size_t)2560 * 32768;          // 83,886,080 B
    const size_t partAll = (size_t)640 * PSTRIDE * 4;     // 10,649,600 B
    const size_t slabB_off = (size_t)1536 * 32768;

    hipLaunchKernelGGL(ce_kernel, dim3(64), dim3(256), 0, stream,
                       output, target, out + 1, ce_rows);

    if (ws_size >= 131072 + slabAll + partAll) {
        // ---------------- one-shot path ----------------
        float* partials = (float*)(slab + slabAll);
        // repack A: 3 feats x 8 r8 x Q=16 = 384 blocks; B: 4 x 8 x 8 = 256
        hipLaunchKernelGGL(repack_kernel, dim3(384), dim3(256), 0, stream,
                           feats_a, slab, 65536, 16);
        hipLaunchKernelGGL(repack_kernel, dim3(256), dim3(256), 0, stream,
                           feats_b, slab + slabB_off, 32768, 8);
        // gram A: 3 x 128 ranges = 384 blocks; B: 4 x 64 = 256 blocks
        hipLaunchKernelGGL(gram_kernel, dim3(384), dim3(256), 0, stream,
                           (const char*)slab, partials, 128, 512);
        hipLaunchKernelGGL(gram_kernel, dim3(256), dim3(256), 0, stream,
                           (const char*)(slab + slabB_off),
                           partials + (size_t)384 * PSTRIDE, 64, 256);
        hipLaunchKernelGGL(reduce_kernel, dim3(448), dim3(256), 0, stream,
                           partials, K, 128, 64, -1);
    } else {
        // ---------------- per-feature fallback (needs ~19.0 MB) ----------------
        float* partials = (float*)(slab + (size_t)512 * 32768);
        for (int f = 0; f < 7; ++f) {
            if (f < 3) {
                const float* X = feats_a + (size_t)f * 64 * 65536;
                hipLaunchKernelGGL(repack_kernel, dim3(256), dim3(256), 0, stream,
                                   X, slab, 65536, 32);
                hipLaunchKernelGGL(gram_kernel, dim3(128), dim3(256), 0, stream,
                                   (const char*)slab, partials, 128, 512);
                hipLaunchKernelGGL(reduce_kernel, dim3(64), dim3(256), 0, stream,
                                   partials, K, 128, 128, f);
            } else {
                const float* X = feats_b + (size_t)(f - 3) * 64 * 32768;
                hipLaunchKernelGGL(repack_kernel, dim3(128), dim3(256), 0, stream,
                                   X, slab, 32768, 16);
                hipLaunchKernelGGL(gram_kernel, dim3(64), dim3(256), 0, stream,
                                   (const char*)slab, partials, 64, 256);
                hipLaunchKernelGGL(reduce_kernel, dim3(64), dim3(256), 0, stream,
                                   partials, K, 64, 64, f);
            }
        }
    }

    hipLaunchKernelGGL(hsic_kernel, dim3(25), dim3(256), 0, stream, K, hsic);
    hipLaunchKernelGGL(final_kernel, dim3(1), dim3(64), 0, stream,
                       hsic, ce_rows, out);
}

// Round 5
// 177.923 us; speedup vs baseline: 1.5137x; 1.5137x over previous
//
#include <hip/hip_runtime.h>
#include <hip/hip_bf16.h>
#include <math.h>

typedef __attribute__((ext_vector_type(8))) short short8;
typedef __attribute__((ext_vector_type(4))) float f32x4;

#define PSTRIDE 4160          // partials row stride in floats (non-pow2)
#define SLAB_A_F 8388608u     // bytes per A feature: 128 chunks * 65536
#define SLAB_B_F 4194304u     // bytes per B feature:  64 chunks * 65536

// round-to-nearest-even fp32 -> bf16 bits
__device__ __forceinline__ unsigned int bf16_rn(float x) {
    unsigned int u = __float_as_uint(x);
    return (u + 0x7FFFu + ((u >> 16) & 1u)) >> 16;
}

// ---------------------------------------------------------------------------
// Kernel 1: per-row cross-entropy + logits pass-through copy.
// ---------------------------------------------------------------------------
__global__ __launch_bounds__(256) void ce_kernel(
    const float* __restrict__ logits, const int* __restrict__ target,
    float* __restrict__ out_copy, float* __restrict__ ce_rows)
{
    const int row = blockIdx.x;
    const float* x = logits + row * 1000;
    const int t = threadIdx.x;
    __shared__ float red[256];

    float m = -INFINITY;
    for (int i = t; i < 1000; i += 256) {
        float v = x[i];
        out_copy[row * 1000 + i] = v;
        m = fmaxf(m, v);
    }
    red[t] = m; __syncthreads();
    for (int s = 128; s > 0; s >>= 1) {
        if (t < s) red[t] = fmaxf(red[t], red[t + s]);
        __syncthreads();
    }
    m = red[0];
    __syncthreads();

    float ssum = 0.f;
    for (int i = t; i < 1000; i += 256) ssum += expf(x[i] - m);
    red[t] = ssum; __syncthreads();
    for (int s = 128; s > 0; s >>= 1) {
        if (t < s) red[t] += red[t + s];
        __syncthreads();
    }
    if (t == 0) {
        double lse = (double)m + log((double)red[0]);
        int tg = target[row];
        ce_rows[row] = (float)(-((double)x[tg] - lse));
    }
}

// ---------------------------------------------------------------------------
// Kernel 2: repack fp32 -> bf16 slab, layout [f][chunk512][row64][k512].
// Unit = (feature, row, 8192-k segment); seg varies fastest across unit ids
// so concurrent blocks read different k-phases of the same row.
// Per unit: 8 clustered 2-KB contiguous wave-reads, convert, 1-KB contiguous
// wave-writes (lane l handles k = l*8). Grid-stride over units.
// ---------------------------------------------------------------------------
__global__ __launch_bounds__(256) void repack_kernel(
    const float* __restrict__ A, const float* __restrict__ B,
    char* __restrict__ slab, int nfA, int nfB)
{
    const int uA = nfA * 512;               // 64 rows * 8 segs
    const int uTot = uA + nfB * 256;        // + 64 rows * 4 segs
    const int t = threadIdx.x;

    for (int u = blockIdx.x; u < uTot; u += gridDim.x) {
        const float* xr;
        char* slabF;
        int row, seg, D;
        if (u < uA) {
            int f = u >> 9, rem = u & 511;
            seg = rem & 7; row = rem >> 3; D = 65536;
            xr = A + ((size_t)(f * 64 + row)) * D;
            slabF = slab + (size_t)f * SLAB_A_F;
        } else {
            int v = u - uA;
            int f = v >> 8, rem = v & 255;
            seg = rem & 3; row = rem >> 2; D = 32768;
            xr = B + ((size_t)(f * 64 + row)) * D;
            slabF = slab + (size_t)nfA * SLAB_A_F + (size_t)f * SLAB_B_F;
        }
        const int k0 = seg * 8192;
        // ---- 8 clustered contiguous loads ----
        float4 va[4], vb[4];
#pragma unroll
        for (int i = 0; i < 4; ++i) {
            const float* p = xr + k0 + i * 2048 + t * 8;
            va[i] = *(const float4*)p;
            vb[i] = *(const float4*)(p + 4);
        }
        // ---- convert + contiguous stores ----
#pragma unroll
        for (int i = 0; i < 4; ++i) {
            float vv[8] = {va[i].x, va[i].y, va[i].z, va[i].w,
                           vb[i].x, vb[i].y, vb[i].z, vb[i].w};
            short8 hv;
#pragma unroll
            for (int j = 0; j < 8; ++j) hv[j] = (short)bf16_rn(vv[j]);
            int kg = k0 + i * 2048 + t * 8;
            int chunk = kg >> 9, kk = kg & 511;
            *(short8*)(slabF + (size_t)chunk * 65536 + row * 1024 + kk * 2) = hv;
        }
    }
}

// ---------------------------------------------------------------------------
// Kernel 3: Gram from slab. Block = (f, chunk range). Per 512-k chunk, wave w
// owns k-window [w*128, w*128+128): 16 clustered b128 loads (each = 16 full
// 64-B lines in a 16-KB window), then 64 MFMAs. No barriers in the loop.
// ---------------------------------------------------------------------------
__global__ __launch_bounds__(256) void gram_kernel(
    const char* __restrict__ slab, float* __restrict__ partials,
    int nfA, int nfB)
{
    __shared__ float kbuf[4096];
    const int blk = blockIdx.x;
    const int f = blk >> 6, local = blk & 63;

    const char* slabF;
    int c0, nchunk;
    if (f < nfA) {
        slabF = slab + (size_t)f * SLAB_A_F;
        c0 = local * 2; nchunk = 2;
    } else {
        slabF = slab + (size_t)nfA * SLAB_A_F + (size_t)(f - nfA) * SLAB_B_F;
        c0 = local; nchunk = 1;
    }

    const int t = threadIdx.x;
    const int wave = t >> 6, lane = t & 63;
    const int m = lane & 15, quad = lane >> 4;
    const int loff = wave * 256 + quad * 16;   // within-row byte offset

    f32x4 acc[4][4];
#pragma unroll
    for (int i = 0; i < 4; ++i)
#pragma unroll
        for (int j = 0; j < 4; ++j) acc[i][j] = (f32x4)0.f;

    for (int ci = 0; ci < nchunk; ++ci) {
        const char* cb = slabF + (size_t)(c0 + ci) * 65536;
        short8 fr[4][4];   // [s][tm]
#pragma unroll
        for (int s = 0; s < 4; ++s)
#pragma unroll
            for (int tm = 0; tm < 4; ++tm)
                fr[s][tm] = *(const short8*)(cb + (tm * 16 + m) * 1024
                                             + loff + s * 64);
#pragma unroll
        for (int s = 0; s < 4; ++s)
#pragma unroll
            for (int tm = 0; tm < 4; ++tm)
#pragma unroll
                for (int tn = 0; tn < 4; ++tn)
                    acc[tm][tn] = __builtin_amdgcn_mfma_f32_16x16x32_bf16(
                        fr[s][tm], fr[s][tn], acc[tm][tn], 0, 0, 0);
    }

    // ---- cross-wave reduce in LDS (C layout validated R2-R4) ----
    __syncthreads();
    if (wave == 0) {
#pragma unroll
        for (int tm = 0; tm < 4; ++tm)
#pragma unroll
            for (int tn = 0; tn < 4; ++tn)
#pragma unroll
                for (int r = 0; r < 4; ++r)
                    kbuf[(tm * 16 + quad * 4 + r) * 64 + tn * 16 + m] = acc[tm][tn][r];
    }
    __syncthreads();
    if (wave != 0) {
#pragma unroll
        for (int tm = 0; tm < 4; ++tm)
#pragma unroll
            for (int tn = 0; tn < 4; ++tn)
#pragma unroll
                for (int r = 0; r < 4; ++r)
                    atomicAdd(&kbuf[(tm * 16 + quad * 4 + r) * 64 + tn * 16 + m],
                              acc[tm][tn][r]);
    }
    __syncthreads();

    float4* outp = (float4*)(partials + (size_t)blk * PSTRIDE);
    const float4* kb4 = (const float4*)kbuf;
    for (int e = t; e < 1024; e += 256) outp[e] = kb4[e];
}

// ---------------------------------------------------------------------------
// Kernel 4: sum 64 partials per feature -> K[f], zero diagonal.
// singleF < 0: grid 448 (f = blk>>6, base = f*64). Else grid 64, base 0.
// ---------------------------------------------------------------------------
__global__ __launch_bounds__(256) void reduce_kernel(
    const float* __restrict__ partials, float* __restrict__ K, int singleF)
{
    __shared__ double red[256];
    int f, eblk, base;
    if (singleF < 0) { f = blockIdx.x >> 6; eblk = blockIdx.x & 63; base = f * 64; }
    else             { f = singleF; eblk = blockIdx.x; base = 0; }
    const int e = (eblk << 6) + (threadIdx.x & 63);
    const int jg = threadIdx.x >> 6;

    double s0 = 0.0, s1 = 0.0;
    for (int j = jg; j < 64; j += 8) {
        s0 += (double)partials[(size_t)(base + j) * PSTRIDE + e];
        s1 += (double)partials[(size_t)(base + j + 4) * PSTRIDE + e];
    }
    red[threadIdx.x] = s0 + s1;
    __syncthreads();
    if (jg == 0) {
        double tot = red[threadIdx.x] + red[threadIdx.x + 64]
                   + red[threadIdx.x + 128] + red[threadIdx.x + 192];
        int rr = e >> 6, cc = e & 63;
        K[f * 4096 + e] = (rr == cc) ? 0.f : (float)tot;
    }
}

// ---------------------------------------------------------------------------
// Kernel 5: one block per (i,j) pair -> unbiased HSIC in fp64.
// ---------------------------------------------------------------------------
__global__ __launch_bounds__(256) void hsic_kernel(
    const float* __restrict__ K, double* __restrict__ hsic_out)
{
    const int p = blockIdx.x;
    int i, j;
    if (p < 9) { i = p / 3; j = p % 3; }
    else       { int q = p - 9; i = 3 + q / 4; j = 3 + q % 4; }
    const float* Ki = K + i * 4096;
    const float* Kj = K + j * 4096;
    const int t = threadIdx.x;

    __shared__ double red[256];
    __shared__ double ri[64], rj[64];

    double local = 0.0;
    for (int e = t; e < 4096; e += 256)
        local += (double)Ki[e] * (double)Kj[e];
    red[t] = local; __syncthreads();
    for (int s = 128; s > 0; s >>= 1) {
        if (t < s) red[t] += red[t + s];
        __syncthreads();
    }

    if (t < 64) {
        double s = 0.0;
        for (int mc = 0; mc < 64; ++mc) s += (double)Ki[t * 64 + mc];
        ri[t] = s;
    } else if (t < 128) {
        int n = t - 64;
        double s = 0.0;
        for (int mc = 0; mc < 64; ++mc) s += (double)Kj[n * 64 + mc];
        rj[n] = s;
    }
    __syncthreads();

    if (t == 0) {
        double tr = red[0];
        double rr = 0.0, si = 0.0, sj = 0.0;
        for (int n = 0; n < 64; ++n) {
            rr += ri[n] * rj[n];
            si += ri[n];
            sj += rj[n];
        }
        const double N = 64.0;
        const double c1 = (N - 1.0) * (N - 2.0);
        const double c2 = N - 2.0;
        const double c3 = N * (N - 3.0);
        hsic_out[p] = (tr + si * sj / c1 - 2.0 * rr / c2) / c3;
    }
}

// ---------------------------------------------------------------------------
// Kernel 6: combine -> loss.
// ---------------------------------------------------------------------------
__global__ __launch_bounds__(64) void final_kernel(
    const double* __restrict__ hsic, const float* __restrict__ ce_rows,
    float* __restrict__ out_loss)
{
    if (threadIdx.x != 0) return;
    double ce = 0.0;
    for (int n = 0; n < 64; ++n) ce += (double)ce_rows[n];
    ce /= 64.0;

    double cka_total = 0.0;
    for (int i = 0; i < 3; ++i)
        for (int j = 0; j < 3; ++j)
            cka_total += hsic[i * 3 + j] / sqrt(hsic[i * 3 + i] * hsic[j * 3 + j]);
    for (int i = 0; i < 4; ++i)
        for (int j = 0; j < 4; ++j)
            cka_total += hsic[9 + i * 4 + j] / sqrt(hsic[9 + i * 4 + i] * hsic[9 + j * 4 + j]);

    out_loss[0] = (float)(ce + 0.1 * cka_total);
}

// ---------------------------------------------------------------------------
extern "C" void kernel_launch(void* const* d_in, const int* in_sizes, int n_in,
                              void* d_out, int out_size, void* d_ws, size_t ws_size,
                              hipStream_t stream)
{
    const float* output  = (const float*)d_in[0];
    const int*   target  = (const int*)d_in[1];
    const float* feats_a = (const float*)d_in[2];
    const float* feats_b = (const float*)d_in[3];
    float* out = (float*)d_out;

    char* ws = (char*)d_ws;
    float*  K       = (float*)ws;                 // 114688 B
    float*  ce_rows = (float*)(ws + 114688);      // 256 B
    double* hsic    = (double*)(ws + 114944);     // 256 B
    char*   slab    = ws + 131072;

    const size_t slabAll = 3 * (size_t)SLAB_A_F + 4 * (size_t)SLAB_B_F; // 41.9 MB
    const size_t partMain = (size_t)448 * PSTRIDE * 4;                  // 7.45 MB
    const size_t mainNeed = 131072 + slabAll + partMain;

    hipLaunchKernelGGL(ce_kernel, dim3(64), dim3(256), 0, stream,
                       output, target, out + 1, ce_rows);

    if (ws_size >= mainNeed) {
        // ---------------- one-shot path ----------------
        float* partials = (float*)(slab + slabAll);
        hipLaunchKernelGGL(repack_kernel, dim3(1280), dim3(256), 0, stream,
                           feats_a, feats_b, slab, 3, 4);
        hipLaunchKernelGGL(gram_kernel, dim3(448), dim3(256), 0, stream,
                           (const char*)slab, partials, 3, 4);
        hipLaunchKernelGGL(reduce_kernel, dim3(448), dim3(256), 0, stream,
                           partials, K, -1);
    } else {
        // ---------------- per-feature fallback (~9.6 MB) ----------------
        float* partials = (float*)(slab + SLAB_A_F);
        for (int f = 0; f < 7; ++f) {
            if (f < 3) {
                const float* X = feats_a + (size_t)f * 64 * 65536;
                hipLaunchKernelGGL(repack_kernel, dim3(256), dim3(256), 0, stream,
                                   X, (const float*)nullptr, slab, 1, 0);
                hipLaunchKernelGGL(gram_kernel, dim3(64), dim3(256), 0, stream,
                                   (const char*)slab, partials, 1, 0);
            } else {
                const float* X = feats_b + (size_t)(f - 3) * 64 * 32768;
                hipLaunchKernelGGL(repack_kernel, dim3(128), dim3(256), 0, stream,
                                   (const float*)nullptr, X, slab, 0, 1);
                hipLaunchKernelGGL(gram_kernel, dim3(64), dim3(256), 0, stream,
                                   (const char*)slab, partials, 0, 1);
            }
            hipLaunchKernelGGL(reduce_kernel, dim3(64), dim3(256), 0, stream,
                               partials, K, f);
        }
    }

    hipLaunchKernelGGL(hsic_kernel, dim3(25), dim3(256), 0, stream, K, hsic);
    hipLaunchKernelGGL(final_kernel, dim3(1), dim3(64), 0, stream,
                       hsic, ce_rows, out);
}